// Round 7
// baseline (243.246 us; speedup 1.0000x reference)
//
#include <hip/hip_runtime.h>
#include <hip/hip_fp16.h>

#define G3 32768          // 32^3 cells per batch row
#define SLAB_CELLS 16384  // half-row slab -> 128 KB of uint2 (fp16x4) in LDS
#define TPB 1024          // threads per block (16 waves)

typedef float f32x4 __attribute__((ext_vector_type(4)));

static __device__ __forceinline__ unsigned pack2h(float a, float b) {
    unsigned short ua = __half_as_ushort(__float2half(a));
    unsigned short ub = __half_as_ushort(__float2half(b));
    return (unsigned)ua | ((unsigned)ub << 16);
}
static __device__ __forceinline__ float lo2f(unsigned u) {
    return __half2float(__ushort_as_half((unsigned short)(u & 0xffffu)));
}
static __device__ __forceinline__ float hi2f(unsigned u) {
    return __half2float(__ushort_as_half((unsigned short)(u >> 16)));
}

// Branchless predicated gather: clamp address, always read LDS, zero the
// contribution through the mask. No divergent branches -> gathers batch.
#define GATHER(RX, RY, RZ, ACC)                                                 \
    {                                                                           \
        float fx = rintf(fminf(fmaxf(((RX) - gmin) * 32.0f, 0.0f), 31.0f));     \
        float fy = rintf(fminf(fmaxf(((RY) - gmin) * 32.0f, 0.0f), 31.0f));     \
        float fz = rintf(fminf(fmaxf(((RZ) - gmin) * 32.0f, 0.0f), 31.0f));     \
        int local = (int)(fx * 1024.0f + fy * 32.0f + fz) - base;               \
        bool inb = (unsigned)local < (unsigned)SLAB_CELLS;                      \
        uint2 u = slab[inb ? local : 0];                                        \
        float m  = inb ? hi2f(u.y) : 0.0f;                                      \
        float dx = ((RX) - lo2f(u.x)) * m;                                      \
        float dy = ((RY) - hi2f(u.x)) * m;                                      \
        float dz = ((RZ) - lo2f(u.y)) * m;                                      \
        ACC += dx*dx + dy*dy + dz*dz;                                           \
    }

#define PROCESS(PX, PY, PZ)                                                     \
    do {                                                                        \
        _Pragma("unroll")                                                       \
        for (int t = 0; t < 3; ++t) {                                           \
            float dist = ((PX)*pnx[t] + (PY)*pny[t] + (PZ)*pnz[t] + pdd[t]) * pinv[t]; \
            float rx = (PX) - 2.0f * dist * pnx[t];                             \
            float ry = (PY) - 2.0f * dist * pny[t];                             \
            float rz = (PZ) - 2.0f * dist * pnz[t];                             \
            GATHER(rx, ry, rz, accR);                                           \
            float tx = 2.0f * (quy[t]*(PZ) - quz[t]*(PY));                      \
            float ty = 2.0f * (quz[t]*(PX) - qux[t]*(PZ));                      \
            float tz = 2.0f * (qux[t]*(PY) - quy[t]*(PX));                      \
            float ox = (PX) + qw[t]*tx + (quy[t]*tz - quz[t]*ty);               \
            float oy = (PY) + qw[t]*ty + (quz[t]*tx - qux[t]*tz);               \
            float oz = (PZ) + qw[t]*tz + (qux[t]*ty - quy[t]*tx);               \
            GATHER(ox, oy, oz, accQ);                                           \
        }                                                                       \
    } while (0)

// Grid = 256 blocks, one per batch row (1 block/CU). Each block loops over the
// row's two slabs, reusing one 128 KB LDS buffer: stage slab s (vectorized f32x4
// reads, fp16-packed LDS writes), sync, evaluate all 6 transforms per point with
// branchless LDS gathers, sync, next slab. Points + params loaded once.
__global__ __launch_bounds__(TPB)
void symloss_row_kernel(const float* __restrict__ points,
                        const float* __restrict__ cp,
                        const float* __restrict__ voxel,
                        const float* __restrict__ plane,
                        const float* __restrict__ quat,
                        float* __restrict__ out,
                        int N, float invB)
{
    __shared__ uint2 slab[SLAB_CELLS];           // 128 KB
    __shared__ float sR[TPB / 64], sQ[TPB / 64];

    const int row = blockIdx.x;

    const float* __restrict__ cpb  = cp     + (size_t)row * (G3 * 3);
    const float* __restrict__ voxb = voxel  + (size_t)row * G3;
    const float* __restrict__ ptb  = points + (size_t)row * (size_t)N * 3;

    // ---- this thread's 4 points, loaded once ----
    const float4* __restrict__ pt4 = reinterpret_cast<const float4*>(ptb);
    const int ngrp = N >> 2;
    float4 q0, q1, q2;
    const bool havePts = (int)threadIdx.x < ngrp;
    if (havePts) {
        q0 = pt4[3 * threadIdx.x + 0];
        q1 = pt4[3 * threadIdx.x + 1];
        q2 = pt4[3 * threadIdx.x + 2];
    }

    // ---- transform parameters (uniform, loaded once) ----
    float pnx[3], pny[3], pnz[3], pdd[3], pinv[3];
    float qw[3], qux[3], quy[3], quz[3];
#pragma unroll
    for (int i = 0; i < 3; ++i) {
        float nx = plane[4*i+0], ny = plane[4*i+1], nz = plane[4*i+2], dd = plane[4*i+3];
        pnx[i] = nx; pny[i] = ny; pnz[i] = nz; pdd[i] = dd;
        pinv[i] = 1.0f / (nx*nx + ny*ny + nz*nz);

        float w  = quat[4*i+0], ux = quat[4*i+1], uy = quat[4*i+2], uz = quat[4*i+3];
        float rn = 1.0f / sqrtf(w*w + ux*ux + uy*uy + uz*uz);
        qw[i] = w*rn; qux[i] = ux*rn; quy[i] = uy*rn; quz[i] = uz*rn;
    }

    const float gmin = -0.484375f;   // -0.5 + 0.5/32, exact in f32
    float accR = 0.0f, accQ = 0.0f;

    // ---- two slab phases over the same LDS buffer ----
    for (int s = 0; s < 2; ++s) {
        const int base = s * SLAB_CELLS;

        const f32x4* __restrict__ cp4 = reinterpret_cast<const f32x4*>(cpb + (size_t)base * 3);
        const f32x4* __restrict__ vx4 = reinterpret_cast<const f32x4*>(voxb + base);
#pragma unroll 2
        for (int gI = threadIdx.x; gI < SLAB_CELLS / 4; gI += TPB) {
            f32x4 v0 = __builtin_nontemporal_load(&cp4[3*gI+0]);
            f32x4 v1 = __builtin_nontemporal_load(&cp4[3*gI+1]);
            f32x4 v2 = __builtin_nontemporal_load(&cp4[3*gI+2]);
            f32x4 w  = __builtin_nontemporal_load(&vx4[gI]);
            uint2 c0; c0.x = pack2h(v0.x, v0.y); c0.y = pack2h(v0.z, 1.0f - w.x);
            uint2 c1; c1.x = pack2h(v0.w, v1.x); c1.y = pack2h(v1.y, 1.0f - w.y);
            uint2 c2; c2.x = pack2h(v1.z, v1.w); c2.y = pack2h(v2.x, 1.0f - w.z);
            uint2 c3; c3.x = pack2h(v2.y, v2.z); c3.y = pack2h(v2.w, 1.0f - w.w);
            slab[4*gI+0] = c0; slab[4*gI+1] = c1;
            slab[4*gI+2] = c2; slab[4*gI+3] = c3;
        }
        __syncthreads();

        if (havePts) {
            PROCESS(q0.x, q0.y, q0.z);
            PROCESS(q0.w, q1.x, q1.y);
            PROCESS(q1.z, q1.w, q2.x);
            PROCESS(q2.y, q2.z, q2.w);
        }
        // generic tail (only taken if N > 4*TPB)
        for (int g4 = threadIdx.x + TPB; g4 < ngrp; g4 += TPB) {
            float4 a0 = pt4[3*g4+0], a1 = pt4[3*g4+1], a2 = pt4[3*g4+2];
            PROCESS(a0.x, a0.y, a0.z);
            PROCESS(a0.w, a1.x, a1.y);
            PROCESS(a1.z, a1.w, a2.x);
            PROCESS(a2.y, a2.z, a2.w);
        }
        __syncthreads();   // LDS reused by next slab
    }

    // ---- reduction: wave shuffle, then LDS across the 16 waves ----
#pragma unroll
    for (int off = 32; off > 0; off >>= 1) {
        accR += __shfl_down(accR, off, 64);
        accQ += __shfl_down(accQ, off, 64);
    }
    int wave = threadIdx.x >> 6;
    int lane = threadIdx.x & 63;
    if (lane == 0) { sR[wave] = accR; sQ[wave] = accQ; }
    __syncthreads();
    if (threadIdx.x == 0) {
        float r = 0.0f, q = 0.0f;
#pragma unroll
        for (int w = 0; w < TPB / 64; ++w) { r += sR[w]; q += sQ[w]; }
        atomicAdd(&out[0], r * invB);   // mean over batch applied here
        atomicAdd(&out[1], q * invB);
    }
}

extern "C" void kernel_launch(void* const* d_in, const int* in_sizes, int n_in,
                              void* d_out, int out_size, void* d_ws, size_t ws_size,
                              hipStream_t stream)
{
    const float* points = (const float*)d_in[0];
    const float* cp     = (const float*)d_in[1];
    const float* voxel  = (const float*)d_in[2];
    const float* plane  = (const float*)d_in[3];
    const float* quat   = (const float*)d_in[4];
    float* out = (float*)d_out;

    int B = in_sizes[2] / G3;                 // 256
    int N = (in_sizes[0] / 3) / B;            // 4096
    float invB = 1.0f / (float)B;

    (void)hipMemsetAsync(out, 0, (size_t)out_size * sizeof(float), stream);

    symloss_row_kernel<<<B, TPB, 0, stream>>>(points, cp, voxel, plane, quat,
                                              out, N, invB);
}